// Round 5
// baseline (334.070 us; speedup 1.0000x reference)
//
#include <hip/hip_runtime.h>
#include <math.h>

#define T_DIM 11
#define HH 1024
#define WW 1024
#define HWSZ (HH*WW)
#define INTR 1022              // interior extent (1..1022 in full image)
#define NSTRIP 511             // 1022 interior cols / 2 per thread

struct FracM { float m[T_DIM][T_DIM]; };

// stencil coefficients (from LAPL / PX / PY), with /DX and /DX^2 folded in
#define LC0 0.34520446044393f        // laplacian corners
#define LC1 0.309591078922457f       // laplacian edges
#define LCC -2.619182157203629f      // laplacian center
#define PA  0.086301115118584f       // deriv corner coeff
#define PB  0.32739776970073f        // deriv edge coeff
#define INV_DX  1024.0f
#define INV_DX2 1048576.0f
#define R_COEF 0.01f

// pack two f32 as bf16 (truncated) into one u32: hi=a, lo=b
__device__ __forceinline__ unsigned int pack_bf2(float a, float b)
{
    return (__float_as_uint(a) & 0xffff0000u) | (__float_as_uint(b) >> 16);
}
__device__ __forceinline__ float unpack_hi(unsigned int r) { return __uint_as_float(r & 0xffff0000u); }
__device__ __forceinline__ float unpack_lo(unsigned int r) { return __uint_as_float(r << 16); }

// fu = D + ucen*gx + vcen*gy - R*lap - f  for a 3x3 window of one channel
__device__ __forceinline__ float residual(
    float x00, float x01, float x02,
    float x10, float x11, float x12,
    float x20, float x21, float x22,
    float ucen, float vcen, float D, float f)
{
    const float lap = (LC0*(x00+x02+x20+x22) + LC1*(x01+x10+x12+x21) + LCC*x11) * INV_DX2;
    const float gx  = (PA*(x02-x00) + PB*(x12-x10) + PA*(x22-x20)) * INV_DX;
    const float gy  = (PA*(x20-x00) + PB*(x21-x01) + PA*(x22-x02)) * INV_DX;
    return D + ucen*gx + vcen*gy - R_COEF*lap - f;
}

__global__ __launch_bounds__(256, 4)
void fused_loss_kernel(const float* __restrict__ uv,   // [T,2,H,W]
                       const float* __restrict__ f1,   // [T,1,H,W]
                       const float* __restrict__ f2,   // [T,1,H,W]
                       double* __restrict__ partial,
                       FracM M)
{
    // each thread: 2 horizontal pixels (one strip), consecutive lanes = consecutive strips
    const int sb = blockIdx.x * 64 + (threadIdx.x & 63);   // strip 0..510
    const int i  = blockIdx.y * 4  + (threadIdx.x >> 6);   // interior row 0..1021

    float acc = 0.0f;

    if (sb < NSTRIP && i < INTR) {
        const int ci = i + 1;
        const int j0 = 1 + 2 * sb;            // full-image col of px0 (odd)
        const int c  = ci * WW + j0;          // center index of px0; c-1 is 8B-aligned

        // bf16-packed center history: hi=px0, lo=px1. 22 regs instead of 44.
        unsigned int hu[T_DIM], hv[T_DIM];

        #pragma unroll
        for (int t = 0; t < T_DIM; ++t) {
            const float* ub = uv + (size_t)(2 * t) * HWSZ;
            const float* vb = ub + HWSZ;

            // window cols j0-1 .. j0+2 as aligned float2 pairs, rows T/M/B
            const float2 uT_L = *(const float2*)(ub + c - WW - 1);
            const float2 uT_R = *(const float2*)(ub + c - WW + 1);
            const float2 uM_L = *(const float2*)(ub + c - 1);
            const float2 uM_R = *(const float2*)(ub + c + 1);
            const float2 uB_L = *(const float2*)(ub + c + WW - 1);
            const float2 uB_R = *(const float2*)(ub + c + WW + 1);

            const float2 vT_L = *(const float2*)(vb + c - WW - 1);
            const float2 vT_R = *(const float2*)(vb + c - WW + 1);
            const float2 vM_L = *(const float2*)(vb + c - 1);
            const float2 vM_R = *(const float2*)(vb + c + 1);
            const float2 vB_L = *(const float2*)(vb + c + WW - 1);
            const float2 vB_R = *(const float2*)(vb + c + WW + 1);

            const float* f1p = f1 + (size_t)t * HWSZ;
            const float* f2p = f2 + (size_t)t * HWSZ;
            const float f1a = f1p[c],     f1b = f1p[c + 1];
            const float f2a = f2p[c],     f2b = f2p[c + 1];

            // centers (exact f32 for current step)
            const float u11a = uM_L.y, u11b = uM_R.x;
            const float v11a = vM_L.y, v11b = vM_R.x;

            // fractional derivative: bf16 history for s<t, exact f32 diagonal s==t
            float Du0 = 0.f, Dv0 = 0.f, Du1 = 0.f, Dv1 = 0.f;
            #pragma unroll
            for (int s = 0; s < t; ++s) {
                const float m = M.m[t][s];
                Du0 += m * unpack_hi(hu[s]); Du1 += m * unpack_lo(hu[s]);
                Dv0 += m * unpack_hi(hv[s]); Dv1 += m * unpack_lo(hv[s]);
            }
            {
                const float m = M.m[t][t];   // row 0 is all zeros -> Du stays 0 at t=0
                Du0 += m * u11a; Du1 += m * u11b;
                Dv0 += m * v11a; Dv1 += m * v11b;
            }
            hu[t] = pack_bf2(u11a, u11b);
            hv[t] = pack_bf2(v11a, v11b);

            // px0: window cols (L.x, L.y, R.x)
            const float fu0 = residual(uT_L.x, uT_L.y, uT_R.x,
                                       uM_L.x, u11a,   uM_R.x,
                                       uB_L.x, uB_L.y, uB_R.x,
                                       u11a, v11a, Du0, f1a);
            const float fv0 = residual(vT_L.x, vT_L.y, vT_R.x,
                                       vM_L.x, v11a,   vM_R.x,
                                       vB_L.x, vB_L.y, vB_R.x,
                                       u11a, v11a, Dv0, f2a);
            // px1: window cols (L.y, R.x, R.y)
            const float fu1 = residual(uT_L.y, uT_R.x, uT_R.y,
                                       uM_L.y, u11b,   uM_R.y,
                                       uB_L.y, uB_R.x, uB_R.y,
                                       u11b, v11b, Du1, f1b);
            const float fv1 = residual(vT_L.y, vT_R.x, vT_R.y,
                                       vM_L.y, v11b,   vM_R.y,
                                       vB_L.y, vB_R.x, vB_R.y,
                                       u11b, v11b, Dv1, f2b);

            acc += fu0*fu0 + fv0*fv0 + fu1*fu1 + fv1*fv1;
        }
    }

    // ---- reduction: wave64 shfl -> LDS -> one fp64 atomic per block ----
    double dacc = (double)acc;
    #pragma unroll
    for (int off = 32; off > 0; off >>= 1)
        dacc += __shfl_down(dacc, off, 64);

    __shared__ double sdata[4];
    const int lane = threadIdx.x & 63;
    const int wid  = threadIdx.x >> 6;
    if (lane == 0) sdata[wid] = dacc;
    __syncthreads();
    if (threadIdx.x == 0) {
        const double tot = sdata[0] + sdata[1] + sdata[2] + sdata[3];
        atomicAdd(partial, tot);
    }
}

__global__ void finalize_kernel(const double* __restrict__ partial, float* __restrict__ out)
{
    const double n = (double)T_DIM * (double)INTR * (double)INTR;
    out[0] = (float)(partial[0] / n);
}

static FracM make_frac_matrix()
{
    const double alpha = 0.5;
    const int n = 9;                      // N_FRAC
    double w[n + 1];
    w[0] = 1.0;
    for (int jj = 1; jj <= n; ++jj)
        w[jj] = pow((double)(jj + 1), 1.0 - alpha) - pow((double)jj, 1.0 - alpha);

    double M[T_DIM][T_DIM] = {};
    for (int i = 1; i <= n + 1; ++i) {
        M[i][i] += w[0];
        M[i][0] -= w[i - 1];
        for (int k = 1; k < i; ++k)
            M[i][k] -= (w[i - k - 1] - w[i - k]);
    }
    const double scale = pow(0.1, -alpha) / tgamma(2.0 - alpha);  // DT^-a / gamma(2-a)

    FracM f;
    for (int i = 0; i < T_DIM; ++i)
        for (int jj = 0; jj < T_DIM; ++jj)
            f.m[i][jj] = (float)(M[i][jj] * scale);
    return f;
}

extern "C" void kernel_launch(void* const* d_in, const int* in_sizes, int n_in,
                              void* d_out, int out_size, void* d_ws, size_t ws_size,
                              hipStream_t stream)
{
    const float* uv = (const float*)d_in[0];   // output [T,2,H,W]
    const float* f1 = (const float*)d_in[1];   // [T,1,H,W]
    const float* f2 = (const float*)d_in[2];   // [T,1,H,W]
    float* out      = (float*)d_out;
    double* partial = (double*)d_ws;

    FracM M = make_frac_matrix();

    hipMemsetAsync(partial, 0, sizeof(double), stream);

    dim3 block(256, 1, 1);
    dim3 grid((NSTRIP + 63) / 64, (INTR + 3) / 4, 1);   // 8 x 256
    fused_loss_kernel<<<grid, block, 0, stream>>>(uv, f1, f2, partial, M);

    finalize_kernel<<<1, 1, 0, stream>>>(partial, out);
}

// Round 8
// 228.090 us; speedup vs baseline: 1.4646x; 1.4646x over previous
//
#include <hip/hip_runtime.h>
#include <math.h>

#define T_DIM 11
#define HH 1024
#define WW 1024
#define HWSZ (HH*WW)
#define INTR 1022              // interior extent (1..1022 in full image)
#define NSTRIP 511             // 1022 interior cols / 2 per thread

struct FracM { float m[T_DIM][T_DIM]; };

// stencil coefficients (from LAPL / PX / PY), with /DX and /DX^2 folded in
#define LC0 0.34520446044393f        // laplacian corners
#define LC1 0.309591078922457f       // laplacian edges
#define LCC -2.619182157203629f      // laplacian center
#define PA  0.086301115118584f       // deriv corner coeff
#define PB  0.32739776970073f        // deriv edge coeff
#define INV_DX  1024.0f
#define INV_DX2 1048576.0f
#define R_COEF 0.01f

// pack two f32 as bf16 (truncated) into one u32: hi=a, lo=b
__device__ __forceinline__ unsigned int pack_bf2(float a, float b)
{
    return (__float_as_uint(a) & 0xffff0000u) | (__float_as_uint(b) >> 16);
}
__device__ __forceinline__ float unpack_hi(unsigned int r) { return __uint_as_float(r & 0xffff0000u); }
__device__ __forceinline__ float unpack_lo(unsigned int r) { return __uint_as_float(r << 16); }

// fu = D + ucen*gx + vcen*gy - R*lap - f  for a 3x3 window of one channel
__device__ __forceinline__ float residual(
    float x00, float x01, float x02,
    float x10, float x11, float x12,
    float x20, float x21, float x22,
    float ucen, float vcen, float D, float f)
{
    const float lap = (LC0*(x00+x02+x20+x22) + LC1*(x01+x10+x12+x21) + LCC*x11) * INV_DX2;
    const float gx  = (PA*(x02-x00) + PB*(x12-x10) + PA*(x22-x20)) * INV_DX;
    const float gy  = (PA*(x20-x00) + PB*(x21-x01) + PA*(x22-x02)) * INV_DX;
    return D + ucen*gx + vcen*gy - R_COEF*lap - f;
}

// NOTE: no min-waves arg! (256,4) empirically clamps the allocator to the
// 64-VGPR bucket and spills ~90+ MB to scratch (Rounds 4 & 5). Let the
// allocator pick; packed history keeps natural pressure near/below 128.
__global__ __launch_bounds__(256)
void fused_loss_kernel(const float* __restrict__ uv,   // [T,2,H,W]
                       const float* __restrict__ f1,   // [T,1,H,W]
                       const float* __restrict__ f2,   // [T,1,H,W]
                       double* __restrict__ partial,
                       FracM M)
{
    // each thread: 2 horizontal pixels (one strip), consecutive lanes = consecutive strips
    const int sb = blockIdx.x * 64 + (threadIdx.x & 63);   // strip 0..510
    const int i  = blockIdx.y * 4  + (threadIdx.x >> 6);   // interior row 0..1021

    float acc = 0.0f;

    if (sb < NSTRIP && i < INTR) {
        const int ci = i + 1;
        const int j0 = 1 + 2 * sb;            // full-image col of px0 (odd)
        const int c  = ci * WW + j0;          // center index of px0; c-1 is 8B-aligned

        // bf16-packed center history: hi=px0, lo=px1. 22 regs instead of 44.
        unsigned int hu[T_DIM], hv[T_DIM];

        #pragma unroll
        for (int t = 0; t < T_DIM; ++t) {
            const float* ub = uv + (size_t)(2 * t) * HWSZ;
            const float* vb = ub + HWSZ;

            // window cols j0-1 .. j0+2 as aligned float2 pairs, rows T/M/B
            const float2 uT_L = *(const float2*)(ub + c - WW - 1);
            const float2 uT_R = *(const float2*)(ub + c - WW + 1);
            const float2 uM_L = *(const float2*)(ub + c - 1);
            const float2 uM_R = *(const float2*)(ub + c + 1);
            const float2 uB_L = *(const float2*)(ub + c + WW - 1);
            const float2 uB_R = *(const float2*)(ub + c + WW + 1);

            const float2 vT_L = *(const float2*)(vb + c - WW - 1);
            const float2 vT_R = *(const float2*)(vb + c - WW + 1);
            const float2 vM_L = *(const float2*)(vb + c - 1);
            const float2 vM_R = *(const float2*)(vb + c + 1);
            const float2 vB_L = *(const float2*)(vb + c + WW - 1);
            const float2 vB_R = *(const float2*)(vb + c + WW + 1);

            const float* f1p = f1 + (size_t)t * HWSZ;
            const float* f2p = f2 + (size_t)t * HWSZ;
            const float f1a = f1p[c],     f1b = f1p[c + 1];
            const float f2a = f2p[c],     f2b = f2p[c + 1];

            // centers (exact f32 for current step)
            const float u11a = uM_L.y, u11b = uM_R.x;
            const float v11a = vM_L.y, v11b = vM_R.x;

            // fractional derivative: bf16 history for s<t, exact f32 diagonal s==t
            float Du0 = 0.f, Dv0 = 0.f, Du1 = 0.f, Dv1 = 0.f;
            #pragma unroll
            for (int s = 0; s < t; ++s) {
                const float m = M.m[t][s];
                Du0 += m * unpack_hi(hu[s]); Du1 += m * unpack_lo(hu[s]);
                Dv0 += m * unpack_hi(hv[s]); Dv1 += m * unpack_lo(hv[s]);
            }
            {
                const float m = M.m[t][t];   // row 0 is all zeros -> Du stays 0 at t=0
                Du0 += m * u11a; Du1 += m * u11b;
                Dv0 += m * v11a; Dv1 += m * v11b;
            }
            hu[t] = pack_bf2(u11a, u11b);
            hv[t] = pack_bf2(v11a, v11b);

            // px0: window cols (L.x, L.y, R.x)
            const float fu0 = residual(uT_L.x, uT_L.y, uT_R.x,
                                       uM_L.x, u11a,   uM_R.x,
                                       uB_L.x, uB_L.y, uB_R.x,
                                       u11a, v11a, Du0, f1a);
            const float fv0 = residual(vT_L.x, vT_L.y, vT_R.x,
                                       vM_L.x, v11a,   vM_R.x,
                                       vB_L.x, vB_L.y, vB_R.x,
                                       u11a, v11a, Dv0, f2a);
            // px1: window cols (L.y, R.x, R.y)
            const float fu1 = residual(uT_L.y, uT_R.x, uT_R.y,
                                       uM_L.y, u11b,   uM_R.y,
                                       uB_L.y, uB_R.x, uB_R.y,
                                       u11b, v11b, Du1, f1b);
            const float fv1 = residual(vT_L.y, vT_R.x, vT_R.y,
                                       vM_L.y, v11b,   vM_R.y,
                                       vB_L.y, vB_R.x, vB_R.y,
                                       u11b, v11b, Dv1, f2b);

            acc += fu0*fu0 + fv0*fv0 + fu1*fu1 + fv1*fv1;
        }
    }

    // ---- reduction: wave64 shfl -> LDS -> one fp64 atomic per block ----
    double dacc = (double)acc;
    #pragma unroll
    for (int off = 32; off > 0; off >>= 1)
        dacc += __shfl_down(dacc, off, 64);

    __shared__ double sdata[4];
    const int lane = threadIdx.x & 63;
    const int wid  = threadIdx.x >> 6;
    if (lane == 0) sdata[wid] = dacc;
    __syncthreads();
    if (threadIdx.x == 0) {
        const double tot = sdata[0] + sdata[1] + sdata[2] + sdata[3];
        atomicAdd(partial, tot);
    }
}

__global__ void finalize_kernel(const double* __restrict__ partial, float* __restrict__ out)
{
    const double n = (double)T_DIM * (double)INTR * (double)INTR;
    out[0] = (float)(partial[0] / n);
}

static FracM make_frac_matrix()
{
    const double alpha = 0.5;
    const int n = 9;                      // N_FRAC
    double w[n + 1];
    w[0] = 1.0;
    for (int jj = 1; jj <= n; ++jj)
        w[jj] = pow((double)(jj + 1), 1.0 - alpha) - pow((double)jj, 1.0 - alpha);

    double M[T_DIM][T_DIM] = {};
    for (int i = 1; i <= n + 1; ++i) {
        M[i][i] += w[0];
        M[i][0] -= w[i - 1];
        for (int k = 1; k < i; ++k)
            M[i][k] -= (w[i - k - 1] - w[i - k]);
    }
    const double scale = pow(0.1, -alpha) / tgamma(2.0 - alpha);  // DT^-a / gamma(2-a)

    FracM f;
    for (int i = 0; i < T_DIM; ++i)
        for (int jj = 0; jj < T_DIM; ++jj)
            f.m[i][jj] = (float)(M[i][jj] * scale);
    return f;
}

extern "C" void kernel_launch(void* const* d_in, const int* in_sizes, int n_in,
                              void* d_out, int out_size, void* d_ws, size_t ws_size,
                              hipStream_t stream)
{
    const float* uv = (const float*)d_in[0];   // output [T,2,H,W]
    const float* f1 = (const float*)d_in[1];   // [T,1,H,W]
    const float* f2 = (const float*)d_in[2];   // [T,1,H,W]
    float* out      = (float*)d_out;
    double* partial = (double*)d_ws;

    FracM M = make_frac_matrix();

    hipMemsetAsync(partial, 0, sizeof(double), stream);

    dim3 block(256, 1, 1);
    dim3 grid((NSTRIP + 63) / 64, (INTR + 3) / 4, 1);   // 8 x 256
    fused_loss_kernel<<<grid, block, 0, stream>>>(uv, f1, f2, partial, M);

    finalize_kernel<<<1, 1, 0, stream>>>(partial, out);
}

// Round 9
// 205.925 us; speedup vs baseline: 1.6223x; 1.1076x over previous
//
#include <hip/hip_runtime.h>
#include <math.h>

#define T_DIM 11
#define HH 1024
#define WW 1024
#define HWSZ (HH*WW)
#define INTR 1022              // interior extent (1..1022 in full image)
#define NSTRIP 511             // 1022 interior cols / 2 per thread

struct FracM { float m[T_DIM][T_DIM]; };

// stencil coefficients (from LAPL / PX / PY), with /DX and /DX^2 folded in
#define LC0 0.34520446044393f        // laplacian corners
#define LC1 0.309591078922457f       // laplacian edges
#define LCC -2.619182157203629f      // laplacian center
#define PA  0.086301115118584f       // deriv corner coeff
#define PB  0.32739776970073f        // deriv edge coeff
#define INV_DX  1024.0f
#define INV_DX2 1048576.0f
#define R_COEF 0.01f

// pack two f32 as bf16 (truncated) into one u32: hi=a, lo=b
__device__ __forceinline__ unsigned int pack_bf2(float a, float b)
{
    return (__float_as_uint(a) & 0xffff0000u) | (__float_as_uint(b) >> 16);
}
__device__ __forceinline__ float unpack_hi(unsigned int r) { return __uint_as_float(r & 0xffff0000u); }
__device__ __forceinline__ float unpack_lo(unsigned int r) { return __uint_as_float(r << 16); }

// fu = D + ucen*gx + vcen*gy - R*lap - f  for a 3x3 window of one channel
__device__ __forceinline__ float residual(
    float x00, float x01, float x02,
    float x10, float x11, float x12,
    float x20, float x21, float x22,
    float ucen, float vcen, float D, float f)
{
    const float lap = (LC0*(x00+x02+x20+x22) + LC1*(x01+x10+x12+x21) + LCC*x11) * INV_DX2;
    const float gx  = (PA*(x02-x00) + PB*(x12-x10) + PA*(x22-x20)) * INV_DX;
    const float gy  = (PA*(x20-x00) + PB*(x21-x01) + PA*(x22-x02)) * INV_DX;
    return D + ucen*gx + vcen*gy - R_COEF*lap - f;
}

// R8: VGPR=136 (8 over the 128 cliff) -> 2 waves/SIMD, latency-bound at 97us.
// Fix: move packed bf16 history to LDS ([s][tid] layout: lane-consecutive =
// bank-consecutive = conflict-free; thread-private columns, no barrier).
// Frees ~22 VGPRs -> target <=128 -> 4 waves/SIMD.
__global__ __launch_bounds__(256)
void fused_loss_kernel(const float* __restrict__ uv,   // [T,2,H,W]
                       const float* __restrict__ f1,   // [T,1,H,W]
                       const float* __restrict__ f2,   // [T,1,H,W]
                       double* __restrict__ partial,
                       FracM M)
{
    __shared__ unsigned int hist_u[T_DIM][256];
    __shared__ unsigned int hist_v[T_DIM][256];

    const int tid = threadIdx.x;
    // each thread: 2 horizontal pixels (one strip), consecutive lanes = consecutive strips
    const int sb = blockIdx.x * 64 + (tid & 63);   // strip 0..510
    const int i  = blockIdx.y * 4  + (tid >> 6);   // interior row 0..1021

    float acc = 0.0f;

    if (sb < NSTRIP && i < INTR) {
        const int ci = i + 1;
        const int j0 = 1 + 2 * sb;            // full-image col of px0 (odd)
        const int c  = ci * WW + j0;          // center index of px0; c-1 is 8B-aligned

        #pragma unroll
        for (int t = 0; t < T_DIM; ++t) {
            const float* ub = uv + (size_t)(2 * t) * HWSZ;
            const float* vb = ub + HWSZ;

            // window cols j0-1 .. j0+2 as aligned float2 pairs, rows T/M/B
            const float2 uT_L = *(const float2*)(ub + c - WW - 1);
            const float2 uT_R = *(const float2*)(ub + c - WW + 1);
            const float2 uM_L = *(const float2*)(ub + c - 1);
            const float2 uM_R = *(const float2*)(ub + c + 1);
            const float2 uB_L = *(const float2*)(ub + c + WW - 1);
            const float2 uB_R = *(const float2*)(ub + c + WW + 1);

            const float2 vT_L = *(const float2*)(vb + c - WW - 1);
            const float2 vT_R = *(const float2*)(vb + c - WW + 1);
            const float2 vM_L = *(const float2*)(vb + c - 1);
            const float2 vM_R = *(const float2*)(vb + c + 1);
            const float2 vB_L = *(const float2*)(vb + c + WW - 1);
            const float2 vB_R = *(const float2*)(vb + c + WW + 1);

            const float* f1p = f1 + (size_t)t * HWSZ;
            const float* f2p = f2 + (size_t)t * HWSZ;
            const float f1a = f1p[c],     f1b = f1p[c + 1];
            const float f2a = f2p[c],     f2b = f2p[c + 1];

            // centers (exact f32 for current step)
            const float u11a = uM_L.y, u11b = uM_R.x;
            const float v11a = vM_L.y, v11b = vM_R.x;

            // fractional derivative: bf16 history (LDS) for s<t, exact f32 diagonal s==t
            float Du0 = 0.f, Dv0 = 0.f, Du1 = 0.f, Dv1 = 0.f;
            #pragma unroll
            for (int s = 0; s < t; ++s) {
                const float m = M.m[t][s];
                const unsigned int ru = hist_u[s][tid];
                const unsigned int rv = hist_v[s][tid];
                Du0 += m * unpack_hi(ru); Du1 += m * unpack_lo(ru);
                Dv0 += m * unpack_hi(rv); Dv1 += m * unpack_lo(rv);
            }
            {
                const float m = M.m[t][t];   // row 0 is all zeros -> Du stays 0 at t=0
                Du0 += m * u11a; Du1 += m * u11b;
                Dv0 += m * v11a; Dv1 += m * v11b;
            }
            hist_u[t][tid] = pack_bf2(u11a, u11b);
            hist_v[t][tid] = pack_bf2(v11a, v11b);

            // px0: window cols (L.x, L.y, R.x)
            const float fu0 = residual(uT_L.x, uT_L.y, uT_R.x,
                                       uM_L.x, u11a,   uM_R.x,
                                       uB_L.x, uB_L.y, uB_R.x,
                                       u11a, v11a, Du0, f1a);
            const float fv0 = residual(vT_L.x, vT_L.y, vT_R.x,
                                       vM_L.x, v11a,   vM_R.x,
                                       vB_L.x, vB_L.y, vB_R.x,
                                       u11a, v11a, Dv0, f2a);
            // px1: window cols (L.y, R.x, R.y)
            const float fu1 = residual(uT_L.y, uT_R.x, uT_R.y,
                                       uM_L.y, u11b,   uM_R.y,
                                       uB_L.y, uB_R.x, uB_R.y,
                                       u11b, v11b, Du1, f1b);
            const float fv1 = residual(vT_L.y, vT_R.x, vT_R.y,
                                       vM_L.y, v11b,   vM_R.y,
                                       vB_L.y, vB_R.x, vB_R.y,
                                       u11b, v11b, Dv1, f2b);

            acc += fu0*fu0 + fv0*fv0 + fu1*fu1 + fv1*fv1;
        }
    }

    // ---- reduction: wave64 shfl -> LDS -> one fp64 atomic per block ----
    double dacc = (double)acc;
    #pragma unroll
    for (int off = 32; off > 0; off >>= 1)
        dacc += __shfl_down(dacc, off, 64);

    __shared__ double sdata[4];
    const int lane = tid & 63;
    const int wid  = tid >> 6;
    if (lane == 0) sdata[wid] = dacc;
    __syncthreads();
    if (tid == 0) {
        const double tot = sdata[0] + sdata[1] + sdata[2] + sdata[3];
        atomicAdd(partial, tot);
    }
}

__global__ void finalize_kernel(const double* __restrict__ partial, float* __restrict__ out)
{
    const double n = (double)T_DIM * (double)INTR * (double)INTR;
    out[0] = (float)(partial[0] / n);
}

static FracM make_frac_matrix()
{
    const double alpha = 0.5;
    const int n = 9;                      // N_FRAC
    double w[n + 1];
    w[0] = 1.0;
    for (int jj = 1; jj <= n; ++jj)
        w[jj] = pow((double)(jj + 1), 1.0 - alpha) - pow((double)jj, 1.0 - alpha);

    double M[T_DIM][T_DIM] = {};
    for (int i = 1; i <= n + 1; ++i) {
        M[i][i] += w[0];
        M[i][0] -= w[i - 1];
        for (int k = 1; k < i; ++k)
            M[i][k] -= (w[i - k - 1] - w[i - k]);
    }
    const double scale = pow(0.1, -alpha) / tgamma(2.0 - alpha);  // DT^-a / gamma(2-a)

    FracM f;
    for (int i = 0; i < T_DIM; ++i)
        for (int jj = 0; jj < T_DIM; ++jj)
            f.m[i][jj] = (float)(M[i][jj] * scale);
    return f;
}

extern "C" void kernel_launch(void* const* d_in, const int* in_sizes, int n_in,
                              void* d_out, int out_size, void* d_ws, size_t ws_size,
                              hipStream_t stream)
{
    const float* uv = (const float*)d_in[0];   // output [T,2,H,W]
    const float* f1 = (const float*)d_in[1];   // [T,1,H,W]
    const float* f2 = (const float*)d_in[2];   // [T,1,H,W]
    float* out      = (float*)d_out;
    double* partial = (double*)d_ws;

    FracM M = make_frac_matrix();

    hipMemsetAsync(partial, 0, sizeof(double), stream);

    dim3 block(256, 1, 1);
    dim3 grid((NSTRIP + 63) / 64, (INTR + 3) / 4, 1);   // 8 x 256
    fused_loss_kernel<<<grid, block, 0, stream>>>(uv, f1, f2, partial, M);

    finalize_kernel<<<1, 1, 0, stream>>>(partial, out);
}